// Round 14
// baseline (782.765 us; speedup 1.0000x reference)
//
#include <hip/hip_runtime.h>

#define KCW 1024     // num codewords
#define DIM 64       // embedding dim
#define ROWS_BLK 256 // rows per block (2 stripes; grid 512)
#define STRIPE 128   // rows per stripe
#define CWTILE 128   // codewords per LDS phase

typedef __attribute__((ext_vector_type(4))) float f32x4;

// ---------------------------------------------------------------------------
// Pre-kernel: cnorm[k] = sum_d codebook[k][d]^2   (1024 floats into d_ws)
// ---------------------------------------------------------------------------
__global__ void __launch_bounds__(256) vq_cnorm_kernel(const float* __restrict__ cb,
                                                       float* __restrict__ cnorm) {
    int k = blockIdx.x * blockDim.x + threadIdx.x;
    if (k < KCW) {
        const float4* c4 = (const float4*)(cb + (size_t)k * DIM);
        float s0 = 0.f, s1 = 0.f, s2 = 0.f, s3 = 0.f;
#pragma unroll
        for (int j = 0; j < DIM / 4; j += 4) {
            float4 a = c4[j + 0];
            float4 b = c4[j + 1];
            float4 c = c4[j + 2];
            float4 d = c4[j + 3];
            s0 += a.x * a.x + a.y * a.y + a.z * a.z + a.w * a.w;
            s1 += b.x * b.x + b.y * b.y + b.z * b.z + b.w * b.w;
            s2 += c.x * c.x + c.y * c.y + c.z * c.z + c.w * c.w;
            s3 += d.x * d.x + d.y * d.y + d.z * d.z + d.w * d.w;
        }
        cnorm[k] = (s0 + s1) + (s2 + s3);
    }
}

// sequential x,y,z,w chain — bit-identical association to prior passing rounds
#define DOT4ACC(acc, av, bv)                                               \
    acc = fmaf((av).w, (bv).w,                                             \
          fmaf((av).z, (bv).z,                                             \
          fmaf((av).y, (bv).y,                                             \
          fmaf((av).x, (bv).x, (acc)))));

// one micro-row n against all 8 col fragments (single operand buffer)
#define ROWS1(n)                                                           \
    DOT4ACC(q##n##a.x, r##n, c0) DOT4ACC(q##n##a.y, r##n, c1)              \
    DOT4ACC(q##n##a.z, r##n, c2) DOT4ACC(q##n##a.w, r##n, c3)              \
    DOT4ACC(q##n##b.x, r##n, c4) DOT4ACC(q##n##b.y, r##n, c5)              \
    DOT4ACC(q##n##b.z, r##n, c6) DOT4ACC(q##n##b.w, r##n, c7)

// phases ascend -> strict < keeps earliest index (= np.argmin)
#define UPROW(n, X)                                                        \
    { float s_ = fmaf(-2.f, q##n##X, cn);                                  \
      if (s_ < best##n) { best##n = s_; bidx##n = cwv; } }

// cn comes from a named per-phase register (cnv0..cnv7)
#define UPCOL(c, X)                                                        \
    { const float cn = cnv##c;                                             \
      const int cwv = cwbase + 8 * (c);                                    \
      UPROW(0, X) UPROW(1, X) UPROW(2, X) UPROW(3, X)                      \
      UPROW(4, X) UPROW(5, X) UPROW(6, X) UPROW(7, X) }

#define MERGEPUT(n)                                                        \
    { int rl = 64 * wr + ty + 8 * (n);                                     \
      sMs[rl * 16 + slot] = best##n; sMi[rl * 16 + slot] = bidx##n; }

// ---------------------------------------------------------------------------
// Register-tiled distance GEMM, streaming argmin. A FROM GLOBAL (vmcnt
// pipe, L1/L2-resident stripe), B from LDS (lgkm pipe) — PIPE-SPLIT.
// R9-R12 post-mortem: main pinned ~350us, VALUBusy ~52%. The LDS pipe
// (16 ds_read_b128/wave/k4 x 8 waves = 1536cy/k4-window on ONE pipe/CU)
// and VALU (1024cy/k4) run ADDITIVELY; occupancy is empirically capped
// at 8 waves/CU in every config, and burst alignment is wall-clock
// (rotation/desync of addresses does nothing — R12). So: split operands
// across pipes. A-rows read straight from global each k4 (x-stripe 32KB
// is L1-resident after first touch; 8 lanes/wave share each address ->
// broadcast); sX staging deleted. Per CU-k4: vm ~1024cy, LDS ~768cy,
// VALU 1024cy — three independent pipes, each <= VALU.
// Unlike R7 (B-from-global, 585us): only 8 long-latency loads/k4 under
// 512 FMA cy, and B stays in LDS so L1 holds only the x-stripe.
// LDS = sC only (32.8KB; merge/sFinal alias into it). VGPR ~90-110
// (<128 cliff). (R13 run died to a container-level infra failure with no
// counters — resubmitting unchanged; acting on infra noise is not
// evidence-driven.) Numerics: identical values, identical FMA chain
// order, ascending phases + strict-< argmin -> bit-identical to R9.
// ---------------------------------------------------------------------------
__global__ void __launch_bounds__(256)
vq_main_kernel(const float* __restrict__ x,
               const float* __restrict__ cb,
               const float* __restrict__ cnorm,
               float* __restrict__ out_discrete,
               float* __restrict__ out_quant) {
    __shared__ float4 sC[CWTILE * 16];   // 32768 B (merge arrays alias this)
    __shared__ int sFinal[STRIPE];       // 512 B          total 33280

    float* sMs = (float*)sC;                 // 128 rows x 16 slots scores
    int* sMi = ((int*)sC) + STRIPE * 16;     // 128 rows x 16 slots indices

    const int tid = threadIdx.x;
    const int wave = tid >> 6;
    const int lane = tid & 63;
    const int wr = wave >> 1;   // row-group 0..1  (64 rows each)
    const int wc = wave & 1;    // cw-group 0..1   (64 cws each)
    const int ty = lane >> 3;   // 0..7
    const int tx = lane & 7;    // 0..7

    const int row0 = blockIdx.x * ROWS_BLK;
    const float4* xg = (const float4*)x;
    const float4* cbg = (const float4*)cb;
    float4* od4 = (float4*)out_discrete;
    float4* oq4 = (float4*)out_quant;

    const int cnb = 64 * wc + tx;          // first cw of this thread in tile
    const int bbase = (64 * wc + tx) * 16; // f4 base of first micro-col
    const int tx2 = tx << 1;
    const int slot = wc * 8 + tx;

    for (int s = 0; s < ROWS_BLK / STRIPE; ++s) {
        const int grow0 = row0 + s * STRIPE;
        // this thread's first A-row, as f4 index; rows n: +n*8 rows = +n*128
        const size_t xb = ((size_t)grow0 + 64 * wr + ty) * 16;

        __syncthreads();  // (A) prior stripe's merge/epilogue readers done

        float best0 = 3.4e38f, best1 = 3.4e38f, best2 = 3.4e38f, best3 = 3.4e38f;
        float best4 = 3.4e38f, best5 = 3.4e38f, best6 = 3.4e38f, best7 = 3.4e38f;
        int bidx0 = 0, bidx1 = 0, bidx2 = 0, bidx3 = 0;
        int bidx4 = 0, bidx5 = 0, bidx6 = 0, bidx7 = 0;

        for (int p = 0; p < KCW / CWTILE; ++p) {
            __syncthreads();  // (B) prior phase's sC readers done

            // ---- per-phase cnorm values -> registers (L2-hot, consumed
            //      ~3000cy later in argmin; latency fully hidden) ----
            const float* cq = cnorm + p * CWTILE + cnb;
            const float cnv0 = cq[0];
            const float cnv1 = cq[8];
            const float cnv2 = cq[16];
            const float cnv3 = cq[24];
            const float cnv4 = cq[32];
            const float cnv5 = cq[40];
            const float cnv6 = cq[48];
            const float cnv7 = cq[56];

            // ---- stage cw tile: 128 cw x 16 f4, swizzled ----
#pragma unroll
            for (int i = 0; i < 8; ++i) {
                int e = i * 256 + tid;
                int c = e >> 4, ch = e & 15;
                sC[c * 16 + (ch ^ ((c & 7) << 1))] =
                    cbg[(size_t)(p * CWTILE + c) * 16 + ch];
            }
            __syncthreads();  // (C) tile staged

            float4 q0a = {0.f, 0.f, 0.f, 0.f}, q0b = {0.f, 0.f, 0.f, 0.f};
            float4 q1a = {0.f, 0.f, 0.f, 0.f}, q1b = {0.f, 0.f, 0.f, 0.f};
            float4 q2a = {0.f, 0.f, 0.f, 0.f}, q2b = {0.f, 0.f, 0.f, 0.f};
            float4 q3a = {0.f, 0.f, 0.f, 0.f}, q3b = {0.f, 0.f, 0.f, 0.f};
            float4 q4a = {0.f, 0.f, 0.f, 0.f}, q4b = {0.f, 0.f, 0.f, 0.f};
            float4 q5a = {0.f, 0.f, 0.f, 0.f}, q5b = {0.f, 0.f, 0.f, 0.f};
            float4 q6a = {0.f, 0.f, 0.f, 0.f}, q6b = {0.f, 0.f, 0.f, 0.f};
            float4 q7a = {0.f, 0.f, 0.f, 0.f}, q7b = {0.f, 0.f, 0.f, 0.f};

            // one k4 slice per iteration: 8 global A-reads (vmcnt, L1-hot)
            // issued first, 8 LDS B-reads (lgkm), then 256 FMAs.
            // Small region -> no remat/spill; two load pipes in parallel.
#pragma unroll 1
            for (int k4 = 0; k4 < 16; ++k4) {
                const float4 r0 = xg[xb + k4 + 0 * 128];
                const float4 r1 = xg[xb + k4 + 1 * 128];
                const float4 r2 = xg[xb + k4 + 2 * 128];
                const float4 r3 = xg[xb + k4 + 3 * 128];
                const float4 r4 = xg[xb + k4 + 4 * 128];
                const float4 r5 = xg[xb + k4 + 5 * 128];
                const float4 r6 = xg[xb + k4 + 6 * 128];
                const float4 r7 = xg[xb + k4 + 7 * 128];
                const int kb_ = k4 ^ tx2;
                const float4 c0 = sC[bbase + kb_ + 0 * 128];
                const float4 c1 = sC[bbase + kb_ + 1 * 128];
                const float4 c2 = sC[bbase + kb_ + 2 * 128];
                const float4 c3 = sC[bbase + kb_ + 3 * 128];
                const float4 c4 = sC[bbase + kb_ + 4 * 128];
                const float4 c5 = sC[bbase + kb_ + 5 * 128];
                const float4 c6 = sC[bbase + kb_ + 6 * 128];
                const float4 c7 = sC[bbase + kb_ + 7 * 128];
                ROWS1(0) ROWS1(1) ROWS1(2) ROWS1(3)
                ROWS1(4) ROWS1(5) ROWS1(6) ROWS1(7)
            }

            // ---- scores + running argmin (cw ascending -> strict < keeps
            //      earliest index, matching np.argmin) ----
            const int cwbase = p * CWTILE + cnb;
            UPCOL(0, a.x) UPCOL(1, a.y) UPCOL(2, a.z) UPCOL(3, a.w)
            UPCOL(4, b.x) UPCOL(5, b.y) UPCOL(6, b.z) UPCOL(7, b.w)
        }

        __syncthreads();  // (D) compute done -> safe to alias sC with merge

        MERGEPUT(0) MERGEPUT(1) MERGEPUT(2) MERGEPUT(3)
        MERGEPUT(4) MERGEPUT(5) MERGEPUT(6) MERGEPUT(7)
        __syncthreads();  // (E)

        if (tid < STRIPE) {
            float bs = sMs[tid * 16];
            int bi = sMi[tid * 16];
#pragma unroll
            for (int j = 1; j < 16; ++j) {
                float sj = sMs[tid * 16 + j];
                int ij = sMi[tid * 16 + j];
                if (sj < bs || (sj == bs && ij < bi)) { bs = sj; bi = ij; }
            }
            sFinal[tid] = bi;
        }
        __syncthreads();  // (F)

        // ---- epilogue: nontemporal streaming stores (outputs never re-read;
        //      keep the 600 MB write stream out of L2) ----
        {
            size_t obase = (size_t)grow0 * (KCW / 4);
            const int col = tid * 4;
            for (int it = 0; it < STRIPE; ++it) {
                int idx = sFinal[it];  // block-uniform per iteration
                f32x4 v;
                v.x = (col + 0 == idx) ? 1.f : 0.f;
                v.y = (col + 1 == idx) ? 1.f : 0.f;
                v.z = (col + 2 == idx) ? 1.f : 0.f;
                v.w = (col + 3 == idx) ? 1.f : 0.f;
                __builtin_nontemporal_store(v, (f32x4*)&od4[obase + (size_t)it * 256 + tid]);
            }
            size_t qbase = (size_t)grow0 * 16;
#pragma unroll
            for (int it = 0; it < 8; ++it) {
                int cnk = it * 256 + tid;
                int r = cnk >> 4;
                int ch = cnk & 15;
                float4 qv = cbg[(size_t)sFinal[r] * 16 + ch];
                __builtin_nontemporal_store(*(f32x4*)&qv, (f32x4*)&oq4[qbase + cnk]);
            }
        }
    }
}

// ---------------------------------------------------------------------------
extern "C" void kernel_launch(void* const* d_in, const int* in_sizes, int n_in,
                              void* d_out, int out_size, void* d_ws, size_t ws_size,
                              hipStream_t stream) {
    const float* x = (const float*)d_in[0];
    const float* cb = (const float*)d_in[1];
    float* cnorm = (float*)d_ws;  // 1024 floats of scratch

    const int n = in_sizes[0];    // 8388608
    const int rows = n / DIM;     // 131072

    float* out_discrete = (float*)d_out;
    float* out_quant = (float*)d_out + (size_t)rows * KCW;

    vq_cnorm_kernel<<<(KCW + 255) / 256, 256, 0, stream>>>(cb, cnorm);
    vq_main_kernel<<<rows / ROWS_BLK, 256, 0, stream>>>(x, cb, cnorm, out_discrete, out_quant);
}

// Round 15
// 757.624 us; speedup vs baseline: 1.0332x; 1.0332x over previous
//
#include <hip/hip_runtime.h>

#define KCW 1024     // num codewords
#define DIM 64       // embedding dim
#define ROWS_BLK 256 // rows per block (2 stripes; grid 512)
#define STRIPE 128   // rows per stripe
#define CWTILE 128   // codewords per LDS phase

typedef __attribute__((ext_vector_type(4))) float f32x4;

// ---------------------------------------------------------------------------
// Pre-kernel: cnorm[k] = sum_d codebook[k][d]^2   (1024 floats into d_ws)
// ---------------------------------------------------------------------------
__global__ void __launch_bounds__(256) vq_cnorm_kernel(const float* __restrict__ cb,
                                                       float* __restrict__ cnorm) {
    int k = blockIdx.x * blockDim.x + threadIdx.x;
    if (k < KCW) {
        const float4* c4 = (const float4*)(cb + (size_t)k * DIM);
        float s0 = 0.f, s1 = 0.f, s2 = 0.f, s3 = 0.f;
#pragma unroll
        for (int j = 0; j < DIM / 4; j += 4) {
            float4 a = c4[j + 0];
            float4 b = c4[j + 1];
            float4 c = c4[j + 2];
            float4 d = c4[j + 3];
            s0 += a.x * a.x + a.y * a.y + a.z * a.z + a.w * a.w;
            s1 += b.x * b.x + b.y * b.y + b.z * b.z + b.w * b.w;
            s2 += c.x * c.x + c.y * c.y + c.z * c.z + c.w * c.w;
            s3 += d.x * d.x + d.y * d.y + d.z * d.z + d.w * d.w;
        }
        cnorm[k] = (s0 + s1) + (s2 + s3);
    }
}

// sequential x,y,z,w chain — bit-identical association to prior passing rounds
#define DOT4ACC(acc, av, bv)                                               \
    acc = fmaf((av).w, (bv).w,                                             \
          fmaf((av).z, (bv).z,                                             \
          fmaf((av).y, (bv).y,                                             \
          fmaf((av).x, (bv).x, (acc)))));

// one micro-row n against all 8 col fragments (single operand buffer)
#define ROWS1(n)                                                           \
    DOT4ACC(q##n##a.x, r##n, c0) DOT4ACC(q##n##a.y, r##n, c1)              \
    DOT4ACC(q##n##a.z, r##n, c2) DOT4ACC(q##n##a.w, r##n, c3)              \
    DOT4ACC(q##n##b.x, r##n, c4) DOT4ACC(q##n##b.y, r##n, c5)              \
    DOT4ACC(q##n##b.z, r##n, c6) DOT4ACC(q##n##b.w, r##n, c7)

// phases ascend -> strict < keeps earliest index (= np.argmin)
#define UPROW(n, X)                                                        \
    { float s_ = fmaf(-2.f, q##n##X, cn);                                  \
      if (s_ < best##n) { best##n = s_; bidx##n = cwv; } }

// cn comes from a named per-phase register (cnv0..cnv7), not LDS
#define UPCOL(c, X)                                                        \
    { const float cn = cnv##c;                                             \
      const int cwv = cwbase + 8 * (c);                                    \
      UPROW(0, X) UPROW(1, X) UPROW(2, X) UPROW(3, X)                      \
      UPROW(4, X) UPROW(5, X) UPROW(6, X) UPROW(7, X) }

#define MERGEPUT(n)                                                        \
    { int rl = 64 * wr + ty + 8 * (n);                                     \
      sMs[rl * 16 + slot] = best##n; sMi[rl * 16 + slot] = bidx##n; }

// ---------------------------------------------------------------------------
// FINAL (session champion, = R11 @ 759us): register-tiled distance GEMM,
// streaming argmin. A AND B from LDS, single operand buffer, k4 loop not
// unrolled, LDS exactly 65536B, cnorm in registers, sFinal aliasing sC.
//
// Session conclusion — structural plateau, constraint written down:
//   main ~350us = ~170us VALU work + ~180us exposed lgkm waits.
//   Hiding the waits needs (a) >2 waves/SIMD — blocked: residency is
//   empirically capped ~8 waves/CU in every config (R7/R8), or (b) >128
//   live VGPRs across the FMA block — blocked: allocator remats at 128
//   (R0/R2) or spills (R1/R3/R5/R6), and >128 allocations regress via
//   occupancy (R10, 164 VGPR -> 433us). Burst desync is nulled by shared
//   LDS-queue service (R12); pipe-split A/vmcnt + B/lgkm is null (R14).
//   Bench additionally carries ~365us fixed harness fill + ~40us overhead.
// Numerics: bit-identical to the original passing kernel (same FMA chain
// order, ascending-cw strict-< argmin).
// ---------------------------------------------------------------------------
__global__ void __launch_bounds__(256)
vq_main_kernel(const float* __restrict__ x,
               const float* __restrict__ cb,
               const float* __restrict__ cnorm,
               float* __restrict__ out_discrete,
               float* __restrict__ out_quant) {
    __shared__ float4 sX[STRIPE * 16];   // 32768 B (merge arrays alias this)
    __shared__ float4 sC[CWTILE * 16];   // 32768 B (sFinal aliases head)
    //                                      total 65536 B exactly

    float* sMs = (float*)sX;                 // 128 rows x 16 slots scores
    int* sMi = ((int*)sX) + STRIPE * 16;     // 128 rows x 16 slots indices
    int* sFinal = (int*)sC;                  // 512 B, aliases sC

    const int tid = threadIdx.x;
    const int wave = tid >> 6;
    const int lane = tid & 63;
    const int wr = wave >> 1;   // row-group 0..1  (64 rows each)
    const int wc = wave & 1;    // cw-group 0..1   (64 cws each)
    const int ty = lane >> 3;   // 0..7
    const int tx = lane & 7;    // 0..7

    const int row0 = blockIdx.x * ROWS_BLK;
    const float4* xg = (const float4*)x;
    const float4* cbg = (const float4*)cb;
    float4* od4 = (float4*)out_discrete;
    float4* oq4 = (float4*)out_quant;

    const int cnb = 64 * wc + tx;          // first cw of this thread in tile
    const int abase = (64 * wr + ty) * 16; // f4 base of first micro-row
    const int bbase = (64 * wc + tx) * 16; // f4 base of first micro-col
    const int ty2 = ty << 1;
    const int tx2 = tx << 1;
    const int slot = wc * 8 + tx;

    for (int s = 0; s < ROWS_BLK / STRIPE; ++s) {
        const int grow0 = row0 + s * STRIPE;

        __syncthreads();  // (A) prior stripe's epilogue readers done

        // ---- stage x-stripe: 128 rows x 16 f4, swizzled ----
#pragma unroll
        for (int i = 0; i < 8; ++i) {
            int e = i * 256 + tid;
            int r = e >> 4, ch = e & 15;
            sX[r * 16 + (ch ^ ((r & 7) << 1))] = xg[(size_t)(grow0 + r) * 16 + ch];
        }

        float best0 = 3.4e38f, best1 = 3.4e38f, best2 = 3.4e38f, best3 = 3.4e38f;
        float best4 = 3.4e38f, best5 = 3.4e38f, best6 = 3.4e38f, best7 = 3.4e38f;
        int bidx0 = 0, bidx1 = 0, bidx2 = 0, bidx3 = 0;
        int bidx4 = 0, bidx5 = 0, bidx6 = 0, bidx7 = 0;

        for (int p = 0; p < KCW / CWTILE; ++p) {
            __syncthreads();  // (B) prior phase's sC readers done

            // ---- per-phase cnorm values -> registers (L2-hot, consumed
            //      ~3000cy later in argmin; latency fully hidden) ----
            const float* cq = cnorm + p * CWTILE + cnb;
            const float cnv0 = cq[0];
            const float cnv1 = cq[8];
            const float cnv2 = cq[16];
            const float cnv3 = cq[24];
            const float cnv4 = cq[32];
            const float cnv5 = cq[40];
            const float cnv6 = cq[48];
            const float cnv7 = cq[56];

            // ---- stage cw tile: 128 cw x 16 f4, swizzled ----
#pragma unroll
            for (int i = 0; i < 8; ++i) {
                int e = i * 256 + tid;
                int c = e >> 4, ch = e & 15;
                sC[c * 16 + (ch ^ ((c & 7) << 1))] =
                    cbg[(size_t)(p * CWTILE + c) * 16 + ch];
            }
            __syncthreads();  // (C) tile staged (covers sX for p==0 too)

            float4 q0a = {0.f, 0.f, 0.f, 0.f}, q0b = {0.f, 0.f, 0.f, 0.f};
            float4 q1a = {0.f, 0.f, 0.f, 0.f}, q1b = {0.f, 0.f, 0.f, 0.f};
            float4 q2a = {0.f, 0.f, 0.f, 0.f}, q2b = {0.f, 0.f, 0.f, 0.f};
            float4 q3a = {0.f, 0.f, 0.f, 0.f}, q3b = {0.f, 0.f, 0.f, 0.f};
            float4 q4a = {0.f, 0.f, 0.f, 0.f}, q4b = {0.f, 0.f, 0.f, 0.f};
            float4 q5a = {0.f, 0.f, 0.f, 0.f}, q5b = {0.f, 0.f, 0.f, 0.f};
            float4 q6a = {0.f, 0.f, 0.f, 0.f}, q6b = {0.f, 0.f, 0.f, 0.f};
            float4 q7a = {0.f, 0.f, 0.f, 0.f}, q7b = {0.f, 0.f, 0.f, 0.f};

            // one k4 slice per iteration: 16 ds_read_b128 batched, partial
            // lgkm waits, then 256 FMAs. Small region -> no remat/spill.
#pragma unroll 1
            for (int k4 = 0; k4 < 16; ++k4) {
                const int ka_ = k4 ^ ty2;
                const int kb_ = k4 ^ tx2;
                // first FMA consumes r0,c0 — issue them first
                const float4 r0 = sX[abase + ka_ + 0 * 128];
                const float4 c0 = sC[bbase + kb_ + 0 * 128];
                const float4 c1 = sC[bbase + kb_ + 1 * 128];
                const float4 c2 = sC[bbase + kb_ + 2 * 128];
                const float4 c3 = sC[bbase + kb_ + 3 * 128];
                const float4 c4 = sC[bbase + kb_ + 4 * 128];
                const float4 c5 = sC[bbase + kb_ + 5 * 128];
                const float4 c6 = sC[bbase + kb_ + 6 * 128];
                const float4 c7 = sC[bbase + kb_ + 7 * 128];
                const float4 r1 = sX[abase + ka_ + 1 * 128];
                const float4 r2 = sX[abase + ka_ + 2 * 128];
                const float4 r3 = sX[abase + ka_ + 3 * 128];
                const float4 r4 = sX[abase + ka_ + 4 * 128];
                const float4 r5 = sX[abase + ka_ + 5 * 128];
                const float4 r6 = sX[abase + ka_ + 6 * 128];
                const float4 r7 = sX[abase + ka_ + 7 * 128];
                ROWS1(0) ROWS1(1) ROWS1(2) ROWS1(3)
                ROWS1(4) ROWS1(5) ROWS1(6) ROWS1(7)
            }

            // ---- scores + running argmin (cw ascending -> strict < keeps
            //      earliest index, matching np.argmin) ----
            const int cwbase = p * CWTILE + cnb;
            UPCOL(0, a.x) UPCOL(1, a.y) UPCOL(2, a.z) UPCOL(3, a.w)
            UPCOL(4, b.x) UPCOL(5, b.y) UPCOL(6, b.z) UPCOL(7, b.w)
        }

        __syncthreads();  // (D) compute done -> safe to alias sX with merge

        MERGEPUT(0) MERGEPUT(1) MERGEPUT(2) MERGEPUT(3)
        MERGEPUT(4) MERGEPUT(5) MERGEPUT(6) MERGEPUT(7)
        __syncthreads();  // (E)

        if (tid < STRIPE) {
            float bs = sMs[tid * 16];
            int bi = sMi[tid * 16];
#pragma unroll
            for (int j = 1; j < 16; ++j) {
                float sj = sMs[tid * 16 + j];
                int ij = sMi[tid * 16 + j];
                if (sj < bs || (sj == bs && ij < bi)) { bs = sj; bi = ij; }
            }
            sFinal[tid] = bi;   // writes sC head; sC dead until next staging
        }
        __syncthreads();  // (F)

        // ---- epilogue: nontemporal streaming stores (outputs never re-read;
        //      keep the 600 MB write stream out of L2) ----
        {
            size_t obase = (size_t)grow0 * (KCW / 4);
            const int col = tid * 4;
            for (int it = 0; it < STRIPE; ++it) {
                int idx = sFinal[it];  // block-uniform per iteration
                f32x4 v;
                v.x = (col + 0 == idx) ? 1.f : 0.f;
                v.y = (col + 1 == idx) ? 1.f : 0.f;
                v.z = (col + 2 == idx) ? 1.f : 0.f;
                v.w = (col + 3 == idx) ? 1.f : 0.f;
                __builtin_nontemporal_store(v, (f32x4*)&od4[obase + (size_t)it * 256 + tid]);
            }
            size_t qbase = (size_t)grow0 * 16;
#pragma unroll
            for (int it = 0; it < 8; ++it) {
                int cnk = it * 256 + tid;
                int r = cnk >> 4;
                int ch = cnk & 15;
                float4 qv = cbg[(size_t)sFinal[r] * 16 + ch];
                __builtin_nontemporal_store(*(f32x4*)&qv, (f32x4*)&oq4[qbase + cnk]);
            }
        }
    }
}

// ---------------------------------------------------------------------------
extern "C" void kernel_launch(void* const* d_in, const int* in_sizes, int n_in,
                              void* d_out, int out_size, void* d_ws, size_t ws_size,
                              hipStream_t stream) {
    const float* x = (const float*)d_in[0];
    const float* cb = (const float*)d_in[1];
    float* cnorm = (float*)d_ws;  // 1024 floats of scratch

    const int n = in_sizes[0];    // 8388608
    const int rows = n / DIM;     // 131072

    float* out_discrete = (float*)d_out;
    float* out_quant = (float*)d_out + (size_t)rows * KCW;

    vq_cnorm_kernel<<<(KCW + 255) / 256, 256, 0, stream>>>(cb, cnorm);
    vq_main_kernel<<<rows / ROWS_BLK, 256, 0, stream>>>(x, cb, cnorm, out_discrete, out_quant);
}